// Round 1
// baseline (209.465 us; speedup 1.0000x reference)
//
#include <hip/hip_runtime.h>

// FusedMultiPool: out[b,s,h,w] = max_{k<K} x[b, idx[s,k], h, w]
// B=32, C=256, H=64, W=64, S=128, K=8. All fp32.
//
// Memory-bound gather-max. One thread per float4 along W.
// gid layout: b (5b) | s (7b) | h (6b) | w4 (4b)  -> 2^22 float4 outputs.
// With 256-thread blocks, s and b are block-uniform -> derive from blockIdx
// so channel indices load as scalar s_load and gathers use SGPR offsets.

constexpr int Bb = 32, Cc = 256, Hh = 64, Ww = 64, Ss = 128, Kk = 8;
constexpr int HW4 = (Hh * Ww) / 4;   // 1024 float4 per channel plane

__global__ __launch_bounds__(256) void fmp_kernel(
    const float4* __restrict__ x4,
    const int*    __restrict__ idx,
    float4*       __restrict__ out4)
{
    const int gid = blockIdx.x * 256 + threadIdx.x;
    const int hw4 = gid & (HW4 - 1);                 // h*16 + w4
    const int s   = (blockIdx.x >> 2) & (Ss - 1);    // 4 blocks per s  (uniform)
    const int b   =  blockIdx.x >> 9;                // 512 blocks per b (uniform)

    const int* __restrict__ ip = idx + s * Kk;       // scalar loads (uniform addr)
    const float4* __restrict__ xb = x4 + (size_t)b * (Cc * HW4) + hw4;

    float4 m = xb[(size_t)ip[0] * HW4];
    #pragma unroll
    for (int k = 1; k < Kk; ++k) {
        const float4 v = xb[(size_t)ip[k] * HW4];
        m.x = fmaxf(m.x, v.x);
        m.y = fmaxf(m.y, v.y);
        m.z = fmaxf(m.z, v.z);
        m.w = fmaxf(m.w, v.w);
    }
    out4[gid] = m;
}

extern "C" void kernel_launch(void* const* d_in, const int* in_sizes, int n_in,
                              void* d_out, int out_size, void* d_ws, size_t ws_size,
                              hipStream_t stream) {
    const float4* x4  = (const float4*)d_in[0];
    const int*    idx = (const int*)d_in[1];
    float4*       o4  = (float4*)d_out;

    // total float4 outputs = 32*128*64*64/4 = 4,194,304 -> 16384 blocks of 256
    const int n4     = Bb * Ss * Hh * Ww / 4;
    const int blocks = n4 / 256;
    fmp_kernel<<<blocks, 256, 0, stream>>>(x4, idx, o4);
}